// Round 1
// baseline (1533.388 us; speedup 1.0000x reference)
//
#include <hip/hip_runtime.h>

typedef unsigned short u16;
typedef __attribute__((ext_vector_type(8))) short short8;
typedef __attribute__((ext_vector_type(4))) float f32x4;

#define H   256
#define H2  512
#define TM  64
#define LNP 264   // LN tile row stride (elements), 16B-aligned rows, breaks bank stride
#define H1P 136   // h1 chunk row stride (elements), 16B-aligned rows
#define GG  64    // num graphs (fixed)

__device__ __forceinline__ u16 f2bf(float f) {
  unsigned int i = __builtin_bit_cast(unsigned int, f);
  unsigned int r = i + 0x7fffu + ((i >> 16) & 1u);
  return (u16)(r >> 16);
}

// Fast GELU (tanh form rewritten as sigmoid): gelu(x) = x * sigmoid(1.5957691216*(x + 0.044715 x^3))
// v_exp_f32 + v_rcp_f32; rel err ~1e-6, invisible under bf16 rounding of h1.
__device__ __forceinline__ float gelu_f(float x) {
  float x2 = x * x;
  float u = x * fmaf(x2, 0.07135481627f, 1.59576912161f);  // = 2z
  float e = __expf(-u);
  return x * __builtin_amdgcn_rcpf(1.0f + e);
}

// Fused prep kernel:
//   blocks [0, 3072):   reorder the six weight matrices into bf16 MFMA B-fragment order
//     out[((n_tile*(K/32) + kk)*64 + lane)*8 + j] = bf16(W[(kk*32 + (lane>>4)*8 + j)*Nw + n_tile*16 + (lane&15)])
//   blocks [3072, ...):  seg_accum — run-accumulated scatter-sum (node_batch sorted)
__global__ void prep(const float* __restrict__ n_w1, const float* __restrict__ n_w2,
                     const float* __restrict__ g_w1, const float* __restrict__ g_w2,
                     const float* __restrict__ e_w1, const float* __restrict__ e_w2,
                     u16* __restrict__ r_nw1, u16* __restrict__ r_nw2,
                     u16* __restrict__ r_gw1, u16* __restrict__ r_gw2,
                     u16* __restrict__ r_ew1, u16* __restrict__ r_ew2,
                     const float* __restrict__ nodeX, const int* __restrict__ batch,
                     float* __restrict__ ssum, float* __restrict__ scnt, int N) {
  const int b = blockIdx.x;
  if (b < 3072) {
    const int m = b >> 9;  // matrix id 0..5 (each matrix: 512 blocks x 256 thr = K*Nw elems)
    const float* W; u16* Outw; int K, Nw;
    switch (m) {
      case 0: W = n_w1; Outw = r_nw1; K = H;  Nw = H2; break;
      case 1: W = n_w2; Outw = r_nw2; K = H2; Nw = H;  break;
      case 2: W = g_w1; Outw = r_gw1; K = H;  Nw = H2; break;
      case 3: W = g_w2; Outw = r_gw2; K = H2; Nw = H;  break;
      case 4: W = e_w1; Outw = r_ew1; K = H;  Nw = H2; break;
      default: W = e_w2; Outw = r_ew2; K = H2; Nw = H;  break;
    }
    const int tid = (b & 511) * 256 + threadIdx.x;
    const int f = tid >> 9;
    const int rsl = tid & 511;
    const int lane = rsl >> 3, j = rsl & 7;
    const int KK = K >> 5;
    const int n_t = f / KK, kk = f - n_t * KK;
    const int k = kk * 32 + (lane >> 4) * 8 + j;
    const int n = n_t * 16 + (lane & 15);
    Outw[tid] = f2bf(W[(size_t)k * Nw + n]);
  } else {
    const int t = (b - 3072) * 256 + threadIdx.x;
    const int c4 = t & 63;
    const int chunk = t >> 6;
    const int n0 = chunk * 8;
    if (n0 >= N) return;
    const int cols = c4 * 4;
    float a0 = 0.f, a1 = 0.f, a2 = 0.f, a3 = 0.f, cnt = 0.f;
    int curg = -1;
    for (int i = 0; i < 8; ++i) {
      const int node = n0 + i;
      if (node >= N) break;
      const int g = batch[node];
      if (g != curg) {
        if (curg >= 0) {
          atomicAdd(&ssum[curg * H + cols + 0], a0);
          atomicAdd(&ssum[curg * H + cols + 1], a1);
          atomicAdd(&ssum[curg * H + cols + 2], a2);
          atomicAdd(&ssum[curg * H + cols + 3], a3);
          if (c4 == 0) atomicAdd(&scnt[curg], cnt);
        }
        curg = g; a0 = a1 = a2 = a3 = 0.f; cnt = 0.f;
      }
      float4 u = *(const float4*)(nodeX + (size_t)node * H + cols);
      a0 += u.x; a1 += u.y; a2 += u.z; a3 += u.w;
      cnt += 1.f;
    }
    if (curg >= 0) {
      atomicAdd(&ssum[curg * H + cols + 0], a0);
      atomicAdd(&ssum[curg * H + cols + 1], a1);
      atomicAdd(&ssum[curg * H + cols + 2], a2);
      atomicAdd(&ssum[curg * H + cols + 3], a3);
      if (c4 == 0) atomicAdd(&scnt[curg], cnt);
    }
  }
}

// Unified fused residual LayerNorm -> FFN(GELU) over all three readouts.
// Block 0: global FFN (inlines seg_finalize: gfeat = ssum/max(cnt,1) — block 0 is gfeat's
// only consumer, so the write->sync->read is safely intra-block).
// Blocks [1, nbE]: edge rows. Blocks (nbE, ...]: node rows.
// f32 I/O, bf16 MFMA internals. 256 threads (4 waves), TM=64 rows/block.
// kk-outer GEMM loops re-read A-fragments from LDS per chunk instead of holding
// a1[2][8] (64 VGPRs) live across the whole loop -> peak regs fit 3 waves/SIMD.
__global__ __launch_bounds__(256, 3) void ffn_all(
    const float* __restrict__ nodeX, const float* __restrict__ edgeX,
    float* __restrict__ gfeat, const float* __restrict__ ssum, const float* __restrict__ scnt,
    const float* __restrict__ n_g, const float* __restrict__ n_b,
    const u16* __restrict__ w1r_n, const float* __restrict__ n_b1,
    const u16* __restrict__ w2r_n, const float* __restrict__ n_b2,
    const float* __restrict__ e_g, const float* __restrict__ e_b,
    const u16* __restrict__ w1r_e, const float* __restrict__ e_b1,
    const u16* __restrict__ w2r_e, const float* __restrict__ e_b2,
    const float* __restrict__ g_g, const float* __restrict__ g_b,
    const u16* __restrict__ w1r_g, const float* __restrict__ g_b1,
    const u16* __restrict__ w2r_g, const float* __restrict__ g_b2,
    float* __restrict__ out_n, float* __restrict__ out_e, float* __restrict__ out_g,
    int N, int Me, int nbE) {
  __shared__ __align__(16) u16 lnA[TM][LNP];
  __shared__ __align__(16) u16 h1s[TM][H1P];

  const int tid = threadIdx.x;
  const int b = blockIdx.x;

  const float* X; const float* gamma; const float* beta;
  const u16* w1r; const float* b1; const u16* w2r; const float* b2;
  float* Out; int M; int row0;

  if (b == 0) {
    // Inline seg_finalize (16384 elems / 256 threads)
    for (int i = tid; i < GG * H; i += 256)
      gfeat[i] = ssum[i] / fmaxf(scnt[i >> 8], 1.0f);
    __syncthreads();
    X = gfeat; gamma = g_g; beta = g_b;
    w1r = w1r_g; b1 = g_b1; w2r = w2r_g; b2 = g_b2;
    Out = out_g; M = GG; row0 = 0;
  } else if (b <= nbE) {
    X = edgeX; gamma = e_g; beta = e_b;
    w1r = w1r_e; b1 = e_b1; w2r = w2r_e; b2 = e_b2;
    Out = out_e; M = Me; row0 = (b - 1) * TM;
  } else {
    X = nodeX; gamma = n_g; beta = n_b;
    w1r = w1r_n; b1 = n_b1; w2r = w2r_n; b2 = n_b2;
    Out = out_n; M = N; row0 = (b - 1 - nbE) * TM;
  }

  // ---- Phase 1: LayerNorm into LDS (bf16) ----
  {
    const int r = tid >> 2, p = tid & 3;
    const int row = row0 + r;
    float s = 0.f, ss = 0.f;
    const float4* xr = (const float4*)(X + (size_t)row * H + p * 64);
    float4 xv[16];
    if (row < M) {
#pragma unroll
      for (int i = 0; i < 16; ++i) {
        xv[i] = xr[i];
        float x0 = xv[i].x, x1 = xv[i].y, x2 = xv[i].z, x3 = xv[i].w;
        s += (x0 + x1) + (x2 + x3);
        ss += (x0 * x0 + x1 * x1) + (x2 * x2 + x3 * x3);
      }
    } else {
#pragma unroll
      for (int i = 0; i < 16; ++i) xv[i] = (float4){0.f, 0.f, 0.f, 0.f};
    }
    s += __shfl_xor(s, 1);  s += __shfl_xor(s, 2);
    ss += __shfl_xor(ss, 1); ss += __shfl_xor(ss, 2);
    const float mean = s * (1.f / H);
    const float var = ss * (1.f / H) - mean * mean;
    const float rstd = rsqrtf(var + 1e-5f);
#pragma unroll
    for (int i = 0; i < 16; ++i) {
      const int col = p * 64 + i * 4;
      float4 gv = ((const float4*)gamma)[col >> 2];
      float4 bv = ((const float4*)beta)[col >> 2];
      ushort4 o;
      o.x = f2bf((xv[i].x - mean) * rstd * gv.x + bv.x);
      o.y = f2bf((xv[i].y - mean) * rstd * gv.y + bv.y);
      o.z = f2bf((xv[i].z - mean) * rstd * gv.z + bv.z);
      o.w = f2bf((xv[i].w - mean) * rstd * gv.w + bv.w);
      *(ushort4*)&lnA[r][col] = o;
    }
  }
  __syncthreads();

  const int wave = tid >> 6, lane = tid & 63;
  const int lrow = lane & 15, q = lane >> 4;
  const int m0 = (wave >> 1) * 2;   // this wave's m-tile pair: {m0, m0+1}
  const int nh = (wave & 1);        // n-half selector

  // GEMM2 accumulators: 2m x 8n tiles, persist across chunks
  f32x4 acc[2][8];
#pragma unroll
  for (int m2 = 0; m2 < 2; ++m2)
#pragma unroll
    for (int nt = 0; nt < 8; ++nt) acc[m2][nt] = (f32x4){0.f, 0.f, 0.f, 0.f};

  for (int c = 0; c < 4; ++c) {
    // ---- GEMM1 (kk-outer): produce gelu(h1) chunk (global cols [c*128, c*128+128)) ----
    f32x4 p[4][2];  // [nt][m2]
#pragma unroll
    for (int nt = 0; nt < 4; ++nt) {
      p[nt][0] = (f32x4){0.f, 0.f, 0.f, 0.f};
      p[nt][1] = (f32x4){0.f, 0.f, 0.f, 0.f};
    }
#pragma unroll
    for (int kk = 0; kk < 8; ++kk) {
      const short8 a0 = *(const short8*)(&lnA[(m0 + 0) * 16 + lrow][q * 8 + kk * 32]);
      const short8 a1 = *(const short8*)(&lnA[(m0 + 1) * 16 + lrow][q * 8 + kk * 32]);
#pragma unroll
      for (int nt = 0; nt < 4; ++nt) {
        const int ng = c * 8 + nh * 4 + nt;   // global n-tile (0..31)
        const short8 bfr = ((const short8*)w1r)[(size_t)(ng * 8 + kk) * 64 + lane];
        p[nt][0] = __builtin_amdgcn_mfma_f32_16x16x32_bf16(a0, bfr, p[nt][0], 0, 0, 0);
        p[nt][1] = __builtin_amdgcn_mfma_f32_16x16x32_bf16(a1, bfr, p[nt][1], 0, 0, 0);
      }
    }
#pragma unroll
    for (int nt = 0; nt < 4; ++nt) {
      const int ng = c * 8 + nh * 4 + nt;
      const int coll = (nh * 4 + nt) * 16 + lrow;   // chunk-local col
      const float bias = b1[ng * 16 + lrow];
#pragma unroll
      for (int rr = 0; rr < 4; ++rr) {
        const int prow = q * 4 + rr;
        h1s[m0 * 16 + prow][coll] = f2bf(gelu_f(p[nt][0][rr] + bias));
        h1s[(m0 + 1) * 16 + prow][coll] = f2bf(gelu_f(p[nt][1][rr] + bias));
      }
    }
    __syncthreads();

    // ---- GEMM2 (kk-outer) partial accumulate over this chunk's 4 k-tiles ----
#pragma unroll
    for (int kk = 0; kk < 4; ++kk) {
      const short8 a0 = *(const short8*)(&h1s[(m0 + 0) * 16 + lrow][q * 8 + kk * 32]);
      const short8 a1 = *(const short8*)(&h1s[(m0 + 1) * 16 + lrow][q * 8 + kk * 32]);
#pragma unroll
      for (int nt = 0; nt < 8; ++nt) {
        const int n = nh * 8 + nt;
        const short8 bfr = ((const short8*)w2r)[(size_t)(n * 16 + c * 4 + kk) * 64 + lane];
        acc[0][nt] = __builtin_amdgcn_mfma_f32_16x16x32_bf16(a0, bfr, acc[0][nt], 0, 0, 0);
        acc[1][nt] = __builtin_amdgcn_mfma_f32_16x16x32_bf16(a1, bfr, acc[1][nt], 0, 0, 0);
      }
    }
    __syncthreads();
  }

  // ---- Epilogue: bias + residual, store f32 ----
#pragma unroll
  for (int nt = 0; nt < 8; ++nt) {
    const int col = (nh * 8 + nt) * 16 + lrow;
    const float bias = b2[col];
#pragma unroll
    for (int m2 = 0; m2 < 2; ++m2) {
#pragma unroll
      for (int rr = 0; rr < 4; ++rr) {
        const int lr = (m0 + m2) * 16 + q * 4 + rr;
        const int row = row0 + lr;
        if (row < M) {
          const size_t idx = (size_t)row * H + col;
          Out[idx] = acc[m2][nt][rr] + bias + X[idx];
        }
      }
    }
  }
}

extern "C" void kernel_launch(void* const* d_in, const int* in_sizes, int n_in,
                              void* d_out, int out_size, void* d_ws, size_t ws_size,
                              hipStream_t stream) {
  const float* nodeX = (const float*)d_in[0];
  const float* edgeX = (const float*)d_in[1];
  const int* batch = (const int*)d_in[2];
  // d_in[3] = num_graphs (G=64, fixed by problem)
  const float* n_g = (const float*)d_in[4];
  const float* n_b = (const float*)d_in[5];
  const float* n_w1 = (const float*)d_in[6];
  const float* n_b1 = (const float*)d_in[7];
  const float* n_w2 = (const float*)d_in[8];
  const float* n_b2 = (const float*)d_in[9];
  const float* g_g = (const float*)d_in[10];
  const float* g_b = (const float*)d_in[11];
  const float* g_w1 = (const float*)d_in[12];
  const float* g_b1 = (const float*)d_in[13];
  const float* g_w2 = (const float*)d_in[14];
  const float* g_b2 = (const float*)d_in[15];
  const float* e_g = (const float*)d_in[16];
  const float* e_b = (const float*)d_in[17];
  const float* e_w1 = (const float*)d_in[18];
  const float* e_b1 = (const float*)d_in[19];
  const float* e_w2 = (const float*)d_in[20];
  const float* e_b2 = (const float*)d_in[21];

  const int N = in_sizes[0] / H;    // 20000
  const int Me = in_sizes[1] / H;   // 320000

  char* wsb = (char*)d_ws;
  u16* w1r_n = (u16*)(wsb + 0);
  u16* w2r_n = (u16*)(wsb + 262144);
  u16* w1r_g = (u16*)(wsb + 524288);
  u16* w2r_g = (u16*)(wsb + 786432);
  u16* w1r_e = (u16*)(wsb + 1048576);
  u16* w2r_e = (u16*)(wsb + 1310720);
  float* ssum = (float*)(wsb + 1572864);    // 64*256 f32
  float* scnt = (float*)(wsb + 1638400);    // 64 f32
  float* gfeat = (float*)(wsb + 1638656);   // 64*256 f32

  float* out_g = (float*)d_out;
  float* out_n = out_g + (size_t)GG * H;
  float* out_e = out_n + (size_t)N * H;

  // Zero scatter buffers
  hipMemsetAsync(wsb + 1572864, 0, 65536 + 256, stream);

  // Kernel 1: weight reorder (6 matrices, 3072 blocks) + seg_accum
  const int segBlocks = (((N + 7) / 8) * 64 + 255) / 256;
  prep<<<3072 + segBlocks, 256, 0, stream>>>(
      n_w1, n_w2, g_w1, g_w2, e_w1, e_w2,
      w1r_n, w2r_n, w1r_g, w2r_g, w1r_e, w2r_e,
      nodeX, batch, ssum, scnt, N);

  // Kernel 2: all three FFN readouts in one grid
  const int nbE = (Me + TM - 1) / TM;   // 5000
  const int nbN = (N + TM - 1) / TM;    // 313
  ffn_all<<<1 + nbE + nbN, 256, 0, stream>>>(
      nodeX, edgeX, gfeat, ssum, scnt,
      n_g, n_b, w1r_n, n_b1, w2r_n, n_b2,
      e_g, e_b, w1r_e, e_b1, w2r_e, e_b2,
      g_g, g_b, w1r_g, g_b1, w2r_g, g_b2,
      out_n, out_e, out_g, N, Me, nbE);
}

// Round 2
// 1296.307 us; speedup vs baseline: 1.1829x; 1.1829x over previous
//
#include <hip/hip_runtime.h>

typedef unsigned short u16;
typedef __attribute__((ext_vector_type(8))) short short8;
typedef __attribute__((ext_vector_type(4))) float f32x4;

#define H   256
#define H2  512
#define TM  64
#define LNP 264   // LN tile row stride (elements), 16B-aligned rows, breaks bank stride
#define H1P 136   // h1 chunk row stride (elements), 16B-aligned rows
#define GG  64    // num graphs (fixed)
#define ACCP 260  // acc staging row stride (f32)

__device__ __forceinline__ u16 f2bf(float f) {
  unsigned int i = __builtin_bit_cast(unsigned int, f);
  unsigned int r = i + 0x7fffu + ((i >> 16) & 1u);
  return (u16)(r >> 16);
}

// Fast GELU (tanh form rewritten as sigmoid): gelu(x) = x * sigmoid(1.5957691216*(x + 0.044715 x^3))
__device__ __forceinline__ float gelu_f(float x) {
  float x2 = x * x;
  float u = x * fmaf(x2, 0.07135481627f, 1.59576912161f);
  float e = __expf(-u);
  return x * __builtin_amdgcn_rcpf(1.0f + e);
}

// Fused prep kernel: blocks [0,3072) reorder weights into MFMA B-fragment order;
// blocks [3072,...) run-accumulated scatter-sum (node_batch sorted).
__global__ void prep(const float* __restrict__ n_w1, const float* __restrict__ n_w2,
                     const float* __restrict__ g_w1, const float* __restrict__ g_w2,
                     const float* __restrict__ e_w1, const float* __restrict__ e_w2,
                     u16* __restrict__ r_nw1, u16* __restrict__ r_nw2,
                     u16* __restrict__ r_gw1, u16* __restrict__ r_gw2,
                     u16* __restrict__ r_ew1, u16* __restrict__ r_ew2,
                     const float* __restrict__ nodeX, const int* __restrict__ batch,
                     float* __restrict__ ssum, float* __restrict__ scnt, int N) {
  const int b = blockIdx.x;
  if (b < 3072) {
    const int m = b >> 9;
    const float* W; u16* Outw; int K, Nw;
    switch (m) {
      case 0: W = n_w1; Outw = r_nw1; K = H;  Nw = H2; break;
      case 1: W = n_w2; Outw = r_nw2; K = H2; Nw = H;  break;
      case 2: W = g_w1; Outw = r_gw1; K = H;  Nw = H2; break;
      case 3: W = g_w2; Outw = r_gw2; K = H2; Nw = H;  break;
      case 4: W = e_w1; Outw = r_ew1; K = H;  Nw = H2; break;
      default: W = e_w2; Outw = r_ew2; K = H2; Nw = H;  break;
    }
    const int tid = (b & 511) * 256 + threadIdx.x;
    const int f = tid >> 9;
    const int rsl = tid & 511;
    const int lane = rsl >> 3, j = rsl & 7;
    const int KK = K >> 5;
    const int n_t = f / KK, kk = f - n_t * KK;
    const int k = kk * 32 + (lane >> 4) * 8 + j;
    const int n = n_t * 16 + (lane & 15);
    Outw[tid] = f2bf(W[(size_t)k * Nw + n]);
  } else {
    const int t = (b - 3072) * 256 + threadIdx.x;
    const int c4 = t & 63;
    const int chunk = t >> 6;
    const int n0 = chunk * 8;
    if (n0 >= N) return;
    const int cols = c4 * 4;
    float a0 = 0.f, a1 = 0.f, a2 = 0.f, a3 = 0.f, cnt = 0.f;
    int curg = -1;
    for (int i = 0; i < 8; ++i) {
      const int node = n0 + i;
      if (node >= N) break;
      const int g = batch[node];
      if (g != curg) {
        if (curg >= 0) {
          atomicAdd(&ssum[curg * H + cols + 0], a0);
          atomicAdd(&ssum[curg * H + cols + 1], a1);
          atomicAdd(&ssum[curg * H + cols + 2], a2);
          atomicAdd(&ssum[curg * H + cols + 3], a3);
          if (c4 == 0) atomicAdd(&scnt[curg], cnt);
        }
        curg = g; a0 = a1 = a2 = a3 = 0.f; cnt = 0.f;
      }
      float4 u = *(const float4*)(nodeX + (size_t)node * H + cols);
      a0 += u.x; a1 += u.y; a2 += u.z; a3 += u.w;
      cnt += 1.f;
    }
    if (curg >= 0) {
      atomicAdd(&ssum[curg * H + cols + 0], a0);
      atomicAdd(&ssum[curg * H + cols + 1], a1);
      atomicAdd(&ssum[curg * H + cols + 2], a2);
      atomicAdd(&ssum[curg * H + cols + 3], a3);
      if (c4 == 0) atomicAdd(&scnt[curg], cnt);
    }
  }
}

// Unified fused residual LayerNorm -> FFN(GELU).
// 512 threads (8 waves), TM=64 rows/block. Wave roles: mq = wave>>2 (2 m-tiles each),
// nq = wave&3 (quarter of the n-range). Same per-block weight traffic as the 4-wave
// version but 24 waves/CU instead of 12 at identical 50 KB LDS.
// Epilogue transposes acc through LDS (lnA region, dead by then) so stores and the
// residual X re-read are full-row coalesced float4s.
__global__ __launch_bounds__(512, 6) void ffn_all(
    const float* __restrict__ nodeX, const float* __restrict__ edgeX,
    float* __restrict__ gfeat, const float* __restrict__ ssum, const float* __restrict__ scnt,
    const float* __restrict__ n_g, const float* __restrict__ n_b,
    const u16* __restrict__ w1r_n, const float* __restrict__ n_b1,
    const u16* __restrict__ w2r_n, const float* __restrict__ n_b2,
    const float* __restrict__ e_g, const float* __restrict__ e_b,
    const u16* __restrict__ w1r_e, const float* __restrict__ e_b1,
    const u16* __restrict__ w2r_e, const float* __restrict__ e_b2,
    const float* __restrict__ g_g, const float* __restrict__ g_b,
    const u16* __restrict__ w1r_g, const float* __restrict__ g_b1,
    const u16* __restrict__ w2r_g, const float* __restrict__ g_b2,
    float* __restrict__ out_n, float* __restrict__ out_e, float* __restrict__ out_g,
    int N, int Me, int nbE) {
  __shared__ __align__(16) u16 lnA[TM][LNP];
  __shared__ __align__(16) u16 h1s[TM][H1P];

  const int tid = threadIdx.x;
  const int b = blockIdx.x;

  const float* X; const float* gamma; const float* beta;
  const u16* w1r; const float* b1; const u16* w2r; const float* b2;
  float* Out; int M; int row0;

  if (b == 0) {
    for (int i = tid; i < GG * H; i += 512)
      gfeat[i] = ssum[i] / fmaxf(scnt[i >> 8], 1.0f);
    __syncthreads();
    X = gfeat; gamma = g_g; beta = g_b;
    w1r = w1r_g; b1 = g_b1; w2r = w2r_g; b2 = g_b2;
    Out = out_g; M = GG; row0 = 0;
  } else if (b <= nbE) {
    X = edgeX; gamma = e_g; beta = e_b;
    w1r = w1r_e; b1 = e_b1; w2r = w2r_e; b2 = e_b2;
    Out = out_e; M = Me; row0 = (b - 1) * TM;
  } else {
    X = nodeX; gamma = n_g; beta = n_b;
    w1r = w1r_n; b1 = n_b1; w2r = w2r_n; b2 = n_b2;
    Out = out_n; M = N; row0 = (b - 1 - nbE) * TM;
  }

  // ---- Phase 1: LayerNorm into LDS (bf16). 8 threads/row, 8 float4 each. ----
  {
    const int r = tid >> 3, p = tid & 7;
    const int row = row0 + r;
    float s = 0.f, ss = 0.f;
    const float4* xr = (const float4*)(X + (size_t)row * H + p * 32);
    float4 xv[8];
    if (row < M) {
#pragma unroll
      for (int i = 0; i < 8; ++i) {
        xv[i] = xr[i];
        float x0 = xv[i].x, x1 = xv[i].y, x2 = xv[i].z, x3 = xv[i].w;
        s += (x0 + x1) + (x2 + x3);
        ss += (x0 * x0 + x1 * x1) + (x2 * x2 + x3 * x3);
      }
    } else {
#pragma unroll
      for (int i = 0; i < 8; ++i) xv[i] = (float4){0.f, 0.f, 0.f, 0.f};
    }
    s += __shfl_xor(s, 1);  s += __shfl_xor(s, 2);  s += __shfl_xor(s, 4);
    ss += __shfl_xor(ss, 1); ss += __shfl_xor(ss, 2); ss += __shfl_xor(ss, 4);
    const float mean = s * (1.f / H);
    const float var = ss * (1.f / H) - mean * mean;
    const float rstd = rsqrtf(var + 1e-5f);
#pragma unroll
    for (int i = 0; i < 8; ++i) {
      const int col = p * 32 + i * 4;
      float4 gv = ((const float4*)gamma)[col >> 2];
      float4 bv = ((const float4*)beta)[col >> 2];
      ushort4 o;
      o.x = f2bf((xv[i].x - mean) * rstd * gv.x + bv.x);
      o.y = f2bf((xv[i].y - mean) * rstd * gv.y + bv.y);
      o.z = f2bf((xv[i].z - mean) * rstd * gv.z + bv.z);
      o.w = f2bf((xv[i].w - mean) * rstd * gv.w + bv.w);
      *(ushort4*)&lnA[r][col] = o;
    }
  }
  __syncthreads();

  const int wave = tid >> 6, lane = tid & 63;
  const int lrow = lane & 15, q = lane >> 4;
  const int mq = wave >> 2;         // m-tile pair: {mq*2, mq*2+1}
  const int nq = wave & 3;          // n-quarter selector
  const int m0 = mq * 2;

  f32x4 acc[2][4];                  // [m2][nt] persist across chunks
#pragma unroll
  for (int m2 = 0; m2 < 2; ++m2)
#pragma unroll
    for (int nt = 0; nt < 4; ++nt) acc[m2][nt] = (f32x4){0.f, 0.f, 0.f, 0.f};

  for (int c = 0; c < 4; ++c) {
    // ---- GEMM1 (kk-outer): gelu(h1) chunk, global cols [c*128, c*128+128) ----
    f32x4 p[2][2];  // [nt][m2]
#pragma unroll
    for (int nt = 0; nt < 2; ++nt) {
      p[nt][0] = (f32x4){0.f, 0.f, 0.f, 0.f};
      p[nt][1] = (f32x4){0.f, 0.f, 0.f, 0.f};
    }
#pragma unroll
    for (int kk = 0; kk < 8; ++kk) {
      const short8 a0 = *(const short8*)(&lnA[(m0 + 0) * 16 + lrow][q * 8 + kk * 32]);
      const short8 a1 = *(const short8*)(&lnA[(m0 + 1) * 16 + lrow][q * 8 + kk * 32]);
#pragma unroll
      for (int nt = 0; nt < 2; ++nt) {
        const int ng = c * 8 + nq * 2 + nt;   // global n-tile (0..31)
        const short8 bfr = ((const short8*)w1r)[(size_t)(ng * 8 + kk) * 64 + lane];
        p[nt][0] = __builtin_amdgcn_mfma_f32_16x16x32_bf16(a0, bfr, p[nt][0], 0, 0, 0);
        p[nt][1] = __builtin_amdgcn_mfma_f32_16x16x32_bf16(a1, bfr, p[nt][1], 0, 0, 0);
      }
    }
#pragma unroll
    for (int nt = 0; nt < 2; ++nt) {
      const int ng = c * 8 + nq * 2 + nt;
      const int coll = (nq * 2 + nt) * 16 + lrow;   // chunk-local col
      const float bias = b1[ng * 16 + lrow];
#pragma unroll
      for (int rr = 0; rr < 4; ++rr) {
        const int prow = q * 4 + rr;
        h1s[m0 * 16 + prow][coll] = f2bf(gelu_f(p[nt][0][rr] + bias));
        h1s[(m0 + 1) * 16 + prow][coll] = f2bf(gelu_f(p[nt][1][rr] + bias));
      }
    }
    __syncthreads();

    // ---- GEMM2 (kk-outer) partial accumulate over this chunk's 4 k-tiles ----
#pragma unroll
    for (int kk = 0; kk < 4; ++kk) {
      const short8 a0 = *(const short8*)(&h1s[(m0 + 0) * 16 + lrow][q * 8 + kk * 32]);
      const short8 a1 = *(const short8*)(&h1s[(m0 + 1) * 16 + lrow][q * 8 + kk * 32]);
#pragma unroll
      for (int nt = 0; nt < 4; ++nt) {
        const int n = nq * 4 + nt;
        const short8 bfr = ((const short8*)w2r)[(size_t)(n * 16 + c * 4 + kk) * 64 + lane];
        acc[0][nt] = __builtin_amdgcn_mfma_f32_16x16x32_bf16(a0, bfr, acc[0][nt], 0, 0, 0);
        acc[1][nt] = __builtin_amdgcn_mfma_f32_16x16x32_bf16(a1, bfr, acc[1][nt], 0, 0, 0);
      }
    }
    __syncthreads();
  }

  // ---- Epilogue: transpose acc through LDS, then coalesced bias+residual+store ----
  float* accS = (float*)&lnA[0][0];   // 32 rows x ACCP f32 (fits in lnA region)
  const int lr_r = tid >> 4;          // 0..31 reader row
  const int pp = tid & 15;            // reader col group (16 floats)
#pragma unroll
  for (int h = 0; h < 2; ++h) {
    if (mq == h) {
#pragma unroll
      for (int m2 = 0; m2 < 2; ++m2)
#pragma unroll
        for (int nt = 0; nt < 4; ++nt) {
          const int col = (nq * 4 + nt) * 16 + lrow;
#pragma unroll
          for (int rr = 0; rr < 4; ++rr)
            accS[(m2 * 16 + q * 4 + rr) * ACCP + col] = acc[m2][nt][rr];
        }
    }
    __syncthreads();
    const int row = row0 + h * 32 + lr_r;
    if (row < M) {
      const float4* xp = (const float4*)(X + (size_t)row * H + pp * 16);
      float4* op = (float4*)(Out + (size_t)row * H + pp * 16);
      const float4* bp = ((const float4*)b2) + pp * 4;
#pragma unroll
      for (int j = 0; j < 4; ++j) {
        const float4 a = *(const float4*)(accS + lr_r * ACCP + pp * 16 + j * 4);
        const float4 xvv = xp[j];
        const float4 bb = bp[j];
        float4 o;
        o.x = a.x + bb.x + xvv.x;
        o.y = a.y + bb.y + xvv.y;
        o.z = a.z + bb.z + xvv.z;
        o.w = a.w + bb.w + xvv.w;
        op[j] = o;
      }
    }
    __syncthreads();
  }
}

extern "C" void kernel_launch(void* const* d_in, const int* in_sizes, int n_in,
                              void* d_out, int out_size, void* d_ws, size_t ws_size,
                              hipStream_t stream) {
  const float* nodeX = (const float*)d_in[0];
  const float* edgeX = (const float*)d_in[1];
  const int* batch = (const int*)d_in[2];
  const float* n_g = (const float*)d_in[4];
  const float* n_b = (const float*)d_in[5];
  const float* n_w1 = (const float*)d_in[6];
  const float* n_b1 = (const float*)d_in[7];
  const float* n_w2 = (const float*)d_in[8];
  const float* n_b2 = (const float*)d_in[9];
  const float* g_g = (const float*)d_in[10];
  const float* g_b = (const float*)d_in[11];
  const float* g_w1 = (const float*)d_in[12];
  const float* g_b1 = (const float*)d_in[13];
  const float* g_w2 = (const float*)d_in[14];
  const float* g_b2 = (const float*)d_in[15];
  const float* e_g = (const float*)d_in[16];
  const float* e_b = (const float*)d_in[17];
  const float* e_w1 = (const float*)d_in[18];
  const float* e_b1 = (const float*)d_in[19];
  const float* e_w2 = (const float*)d_in[20];
  const float* e_b2 = (const float*)d_in[21];

  const int N = in_sizes[0] / H;    // 20000
  const int Me = in_sizes[1] / H;   // 320000

  char* wsb = (char*)d_ws;
  u16* w1r_n = (u16*)(wsb + 0);
  u16* w2r_n = (u16*)(wsb + 262144);
  u16* w1r_g = (u16*)(wsb + 524288);
  u16* w2r_g = (u16*)(wsb + 786432);
  u16* w1r_e = (u16*)(wsb + 1048576);
  u16* w2r_e = (u16*)(wsb + 1310720);
  float* ssum = (float*)(wsb + 1572864);    // 64*256 f32
  float* scnt = (float*)(wsb + 1638400);    // 64 f32
  float* gfeat = (float*)(wsb + 1638656);   // 64*256 f32

  float* out_g = (float*)d_out;
  float* out_n = out_g + (size_t)GG * H;
  float* out_e = out_n + (size_t)N * H;

  hipMemsetAsync(wsb + 1572864, 0, 65536 + 256, stream);

  const int segBlocks = (((N + 7) / 8) * 64 + 255) / 256;
  prep<<<3072 + segBlocks, 256, 0, stream>>>(
      n_w1, n_w2, g_w1, g_w2, e_w1, e_w2,
      w1r_n, w2r_n, w1r_g, w2r_g, w1r_e, w2r_e,
      nodeX, batch, ssum, scnt, N);

  const int nbE = (Me + TM - 1) / TM;   // 5000
  const int nbN = (N + TM - 1) / TM;    // 313
  ffn_all<<<1 + nbE + nbN, 512, 0, stream>>>(
      nodeX, edgeX, gfeat, ssum, scnt,
      n_g, n_b, w1r_n, n_b1, w2r_n, n_b2,
      e_g, e_b, w1r_e, e_b1, w2r_e, e_b2,
      g_g, g_b, w1r_g, g_b1, w2r_g, g_b2,
      out_n, out_e, out_g, N, Me, nbE);
}

// Round 3
// 1083.073 us; speedup vs baseline: 1.4158x; 1.1969x over previous
//
#include <hip/hip_runtime.h>

typedef unsigned short u16;
typedef __attribute__((ext_vector_type(8))) short short8;
typedef __attribute__((ext_vector_type(4))) float f32x4;

#define H   256
#define H2  512
#define TM  64
#define LNP 264   // LN tile row stride (u16), 16B-aligned rows
#define H1P 136   // h1 chunk row stride (u16), 16B-aligned rows
#define ACCP 264  // acc staging row stride (f32)
#define GG  64    // num graphs (fixed)

__device__ __forceinline__ u16 f2bf(float f) {
  unsigned int i = __builtin_bit_cast(unsigned int, f);
  unsigned int r = i + 0x7fffu + ((i >> 16) & 1u);
  return (u16)(r >> 16);
}

// Fast GELU (tanh form rewritten as sigmoid): gelu(x) = x * sigmoid(1.5957691216*(x + 0.044715 x^3))
__device__ __forceinline__ float gelu_f(float x) {
  float x2 = x * x;
  float u = x * fmaf(x2, 0.07135481627f, 1.59576912161f);
  float e = __expf(-u);
  return x * __builtin_amdgcn_rcpf(1.0f + e);
}

// Fused prep kernel:
//   blocks [0,3072): reorder weights into MFMA B-fragment order
//   blocks [3072,3136): per-graph segment mean (binary search on sorted batch, no atomics)
__global__ void prep(const float* __restrict__ n_w1, const float* __restrict__ n_w2,
                     const float* __restrict__ g_w1, const float* __restrict__ g_w2,
                     const float* __restrict__ e_w1, const float* __restrict__ e_w2,
                     u16* __restrict__ r_nw1, u16* __restrict__ r_nw2,
                     u16* __restrict__ r_gw1, u16* __restrict__ r_gw2,
                     u16* __restrict__ r_ew1, u16* __restrict__ r_ew2,
                     const float* __restrict__ nodeX, const int* __restrict__ batch,
                     float* __restrict__ gfeat, int N) {
  const int b = blockIdx.x;
  if (b < 3072) {
    const int m = b >> 9;
    const float* W; u16* Outw; int K, Nw;
    switch (m) {
      case 0: W = n_w1; Outw = r_nw1; K = H;  Nw = H2; break;
      case 1: W = n_w2; Outw = r_nw2; K = H2; Nw = H;  break;
      case 2: W = g_w1; Outw = r_gw1; K = H;  Nw = H2; break;
      case 3: W = g_w2; Outw = r_gw2; K = H2; Nw = H;  break;
      case 4: W = e_w1; Outw = r_ew1; K = H;  Nw = H2; break;
      default: W = e_w2; Outw = r_ew2; K = H2; Nw = H;  break;
    }
    const int tid = (b & 511) * 256 + threadIdx.x;
    const int f = tid >> 9;
    const int rsl = tid & 511;
    const int lane = rsl >> 3, j = rsl & 7;
    const int KK = K >> 5;
    const int n_t = f / KK, kk = f - n_t * KK;
    const int k = kk * 32 + (lane >> 4) * 8 + j;
    const int n = n_t * 16 + (lane & 15);
    Outw[tid] = f2bf(W[(size_t)k * Nw + n]);
  } else {
    const int g = b - 3072;             // graph id 0..63
    // lower_bound(batch, g) and lower_bound(batch, g+1) on sorted batch
    int l = 0, r = N;
    while (l < r) { int mm = (l + r) >> 1; if (batch[mm] < g) l = mm + 1; else r = mm; }
    const int lo = l;
    r = N;
    while (l < r) { int mm = (l + r) >> 1; if (batch[mm] < g + 1) l = mm + 1; else r = mm; }
    const int hi = l;
    const int col = threadIdx.x;        // 256 threads, one column each
    float s = 0.f;
    for (int rw = lo; rw < hi; ++rw)
      s += __builtin_nontemporal_load(nodeX + (size_t)rw * H + col);
    gfeat[g * H + col] = s / fmaxf((float)(hi - lo), 1.0f);
  }
}

// Unified fused residual LayerNorm -> FFN(GELU).
// 512 threads (8 waves), TM=64 rows/block. Each wave owns ALL 4 m-tiles and:
//   GEMM1: 1 n-tile per chunk (ng = c*8+wave)  -> each B-frag load feeds 4 MFMAs
//   GEMM2: 2 n-tiles (wave*2, wave*2+1)        -> same 4:1 MFMA:load ratio
// B-fragments explicitly preloaded into bf[8]/bg[8] (static unrolled indices);
// GEMM2's loads issue before the gelu+barrier so latency hides under LDS work.
// Epilogue: acc transposed through LDS (lnA region, dead), then whole-row
// coalesced nontemporal read/modify/write (1KB per wave instruction).
__global__ __launch_bounds__(512, 5) void ffn_all(
    const float* __restrict__ nodeX, const float* __restrict__ edgeX,
    const float* __restrict__ gfeat,
    const float* __restrict__ n_g, const float* __restrict__ n_b,
    const u16* __restrict__ w1r_n, const float* __restrict__ n_b1,
    const u16* __restrict__ w2r_n, const float* __restrict__ n_b2,
    const float* __restrict__ e_g, const float* __restrict__ e_b,
    const u16* __restrict__ w1r_e, const float* __restrict__ e_b1,
    const u16* __restrict__ w2r_e, const float* __restrict__ e_b2,
    const float* __restrict__ g_g, const float* __restrict__ g_b,
    const u16* __restrict__ w1r_g, const float* __restrict__ g_b1,
    const u16* __restrict__ w2r_g, const float* __restrict__ g_b2,
    float* __restrict__ out_n, float* __restrict__ out_e, float* __restrict__ out_g,
    int N, int Me, int nbE) {
  __shared__ __align__(16) u16 lnA[TM][LNP];
  __shared__ __align__(16) u16 h1s[TM][H1P];

  const int tid = threadIdx.x;
  const int b = blockIdx.x;

  const float* X; const float* gamma; const float* beta;
  const u16* w1r; const float* b1; const u16* w2r; const float* b2;
  float* Out; int M; int row0;

  if (b == 0) {
    X = gfeat; gamma = g_g; beta = g_b;
    w1r = w1r_g; b1 = g_b1; w2r = w2r_g; b2 = g_b2;
    Out = out_g; M = GG; row0 = 0;
  } else if (b <= nbE) {
    X = edgeX; gamma = e_g; beta = e_b;
    w1r = w1r_e; b1 = e_b1; w2r = w2r_e; b2 = e_b2;
    Out = out_e; M = Me; row0 = (b - 1) * TM;
  } else {
    X = nodeX; gamma = n_g; beta = n_b;
    w1r = w1r_n; b1 = n_b1; w2r = w2r_n; b2 = n_b2;
    Out = out_n; M = N; row0 = (b - 1 - nbE) * TM;
  }

  // ---- Phase 1: LayerNorm into LDS (bf16). 8 threads/row. ----
  {
    const int r = tid >> 3, p = tid & 7;
    const int row = row0 + r;
    float s = 0.f, ss = 0.f;
    f32x4 xv[8];
    if (row < M) {
      const f32x4* xr = (const f32x4*)(X + (size_t)row * H + p * 32);
#pragma unroll
      for (int i = 0; i < 8; ++i) {
        xv[i] = __builtin_nontemporal_load(xr + i);
        s += (xv[i][0] + xv[i][1]) + (xv[i][2] + xv[i][3]);
        ss += (xv[i][0] * xv[i][0] + xv[i][1] * xv[i][1]) +
              (xv[i][2] * xv[i][2] + xv[i][3] * xv[i][3]);
      }
    } else {
#pragma unroll
      for (int i = 0; i < 8; ++i) xv[i] = (f32x4){0.f, 0.f, 0.f, 0.f};
    }
    s += __shfl_xor(s, 1);  s += __shfl_xor(s, 2);  s += __shfl_xor(s, 4);
    ss += __shfl_xor(ss, 1); ss += __shfl_xor(ss, 2); ss += __shfl_xor(ss, 4);
    const float mean = s * (1.f / H);
    const float var = ss * (1.f / H) - mean * mean;
    const float rstd = rsqrtf(var + 1e-5f);
#pragma unroll
    for (int i = 0; i < 8; ++i) {
      const int col = p * 32 + i * 4;
      f32x4 gv = *(const f32x4*)(gamma + col);
      f32x4 bv = *(const f32x4*)(beta + col);
      ushort4 o;
      o.x = f2bf((xv[i][0] - mean) * rstd * gv[0] + bv[0]);
      o.y = f2bf((xv[i][1] - mean) * rstd * gv[1] + bv[1]);
      o.z = f2bf((xv[i][2] - mean) * rstd * gv[2] + bv[2]);
      o.w = f2bf((xv[i][3] - mean) * rstd * gv[3] + bv[3]);
      *(ushort4*)&lnA[r][col] = o;
    }
  }
  __syncthreads();

  const int wave = tid >> 6, lane = tid & 63;
  const int lrow = lane & 15, q = lane >> 4;

  f32x4 acc[4][2];                  // [m-tile][n-tile] persist across chunks
#pragma unroll
  for (int mt = 0; mt < 4; ++mt) {
    acc[mt][0] = (f32x4){0.f, 0.f, 0.f, 0.f};
    acc[mt][1] = (f32x4){0.f, 0.f, 0.f, 0.f};
  }

  for (int c = 0; c < 4; ++c) {
    // ---- GEMM1: this wave produces h1 cols for n-tile ng = c*8+wave ----
    const int ng = c * 8 + wave;
    short8 bf[8];
    {
      const short8* wp = (const short8*)w1r + (size_t)(ng * 8) * 64 + lane;
#pragma unroll
      for (int kk = 0; kk < 8; ++kk) bf[kk] = wp[kk * 64];
    }
    const float bias1 = b1[ng * 16 + lrow];

    f32x4 p[4];
#pragma unroll
    for (int mt = 0; mt < 4; ++mt) p[mt] = (f32x4){0.f, 0.f, 0.f, 0.f};
#pragma unroll
    for (int kk = 0; kk < 8; ++kk) {
      short8 a[4];
#pragma unroll
      for (int mt = 0; mt < 4; ++mt)
        a[mt] = *(const short8*)(&lnA[mt * 16 + lrow][q * 8 + kk * 32]);
#pragma unroll
      for (int mt = 0; mt < 4; ++mt)
        p[mt] = __builtin_amdgcn_mfma_f32_16x16x32_bf16(a[mt], bf[kk], p[mt], 0, 0, 0);
    }

    // ---- Issue GEMM2 B loads now: latency hides under gelu + barrier ----
    short8 bg[8];   // [nt*4 + kk]
    {
      const short8* wp2 = (const short8*)w2r + lane;
#pragma unroll
      for (int i = 0; i < 8; ++i) {
        const int nt = i >> 2, kk = i & 3;
        bg[i] = wp2[(size_t)((wave * 2 + nt) * 16 + c * 4 + kk) * 64];
      }
    }

    // ---- gelu + write h1 chunk cols [wave*16, wave*16+16) ----
#pragma unroll
    for (int mt = 0; mt < 4; ++mt)
#pragma unroll
      for (int rr = 0; rr < 4; ++rr)
        h1s[mt * 16 + q * 4 + rr][wave * 16 + lrow] = f2bf(gelu_f(p[mt][rr] + bias1));
    __syncthreads();

    // ---- GEMM2: accumulate this chunk's 4 k-tiles into acc ----
#pragma unroll
    for (int kk = 0; kk < 4; ++kk) {
      short8 a2[4];
#pragma unroll
      for (int mt = 0; mt < 4; ++mt)
        a2[mt] = *(const short8*)(&h1s[mt * 16 + lrow][q * 8 + kk * 32]);
#pragma unroll
      for (int mt = 0; mt < 4; ++mt) {
        acc[mt][0] = __builtin_amdgcn_mfma_f32_16x16x32_bf16(a2[mt], bg[kk], acc[mt][0], 0, 0, 0);
        acc[mt][1] = __builtin_amdgcn_mfma_f32_16x16x32_bf16(a2[mt], bg[4 + kk], acc[mt][1], 0, 0, 0);
      }
    }
    __syncthreads();
  }

  // ---- Epilogue: LDS transpose (lnA region is dead), coalesced whole-row I/O ----
  float* accS = (float*)&lnA[0][0];    // 32 rows x ACCP f32 = 33792B <= lnA size
  const f32x4 b2v = *((const f32x4*)b2 + lane);
#pragma unroll
  for (int h = 0; h < 2; ++h) {
#pragma unroll
    for (int m2 = 0; m2 < 2; ++m2)
#pragma unroll
      for (int nt = 0; nt < 2; ++nt)
#pragma unroll
        for (int rr = 0; rr < 4; ++rr)
          accS[(m2 * 16 + q * 4 + rr) * ACCP + (wave * 2 + nt) * 16 + lrow] =
              acc[2 * h + m2][nt][rr];
    __syncthreads();
#pragma unroll
    for (int rj = 0; rj < 4; ++rj) {
      const int lr = wave * 4 + rj;
      const int row = row0 + h * 32 + lr;
      if (row < M) {
        const f32x4 a = *(const f32x4*)(accS + lr * ACCP + lane * 4);
        const f32x4 xvv = __builtin_nontemporal_load((const f32x4*)(X + (size_t)row * H) + lane);
        f32x4 o = a + b2v + xvv;
        __builtin_nontemporal_store(o, (f32x4*)(Out + (size_t)row * H) + lane);
      }
    }
    __syncthreads();
  }
}

extern "C" void kernel_launch(void* const* d_in, const int* in_sizes, int n_in,
                              void* d_out, int out_size, void* d_ws, size_t ws_size,
                              hipStream_t stream) {
  const float* nodeX = (const float*)d_in[0];
  const float* edgeX = (const float*)d_in[1];
  const int* batch = (const int*)d_in[2];
  const float* n_g = (const float*)d_in[4];
  const float* n_b = (const float*)d_in[5];
  const float* n_w1 = (const float*)d_in[6];
  const float* n_b1 = (const float*)d_in[7];
  const float* n_w2 = (const float*)d_in[8];
  const float* n_b2 = (const float*)d_in[9];
  const float* g_g = (const float*)d_in[10];
  const float* g_b = (const float*)d_in[11];
  const float* g_w1 = (const float*)d_in[12];
  const float* g_b1 = (const float*)d_in[13];
  const float* g_w2 = (const float*)d_in[14];
  const float* g_b2 = (const float*)d_in[15];
  const float* e_g = (const float*)d_in[16];
  const float* e_b = (const float*)d_in[17];
  const float* e_w1 = (const float*)d_in[18];
  const float* e_b1 = (const float*)d_in[19];
  const float* e_w2 = (const float*)d_in[20];
  const float* e_b2 = (const float*)d_in[21];

  const int N = in_sizes[0] / H;    // 20000
  const int Me = in_sizes[1] / H;   // 320000

  char* wsb = (char*)d_ws;
  u16* w1r_n = (u16*)(wsb + 0);
  u16* w2r_n = (u16*)(wsb + 262144);
  u16* w1r_g = (u16*)(wsb + 524288);
  u16* w2r_g = (u16*)(wsb + 786432);
  u16* w1r_e = (u16*)(wsb + 1048576);
  u16* w2r_e = (u16*)(wsb + 1310720);
  float* gfeat = (float*)(wsb + 1572864);   // 64*256 f32

  float* out_g = (float*)d_out;
  float* out_n = out_g + (size_t)GG * H;
  float* out_e = out_n + (size_t)N * H;

  // Kernel 1: weight reorder (3072 blocks) + per-graph segment mean (64 blocks)
  prep<<<3072 + GG, 256, 0, stream>>>(
      n_w1, n_w2, g_w1, g_w2, e_w1, e_w2,
      w1r_n, w2r_n, w1r_g, w2r_g, w1r_e, w2r_e,
      nodeX, batch, gfeat, N);

  // Kernel 2: all three FFN readouts in one grid
  const int nbE = (Me + TM - 1) / TM;   // 5000
  const int nbN = (N + TM - 1) / TM;    // 313
  ffn_all<<<1 + nbE + nbN, 512, 0, stream>>>(
      nodeX, edgeX, gfeat,
      n_g, n_b, w1r_n, n_b1, w2r_n, n_b2,
      e_g, e_b, w1r_e, e_b1, w2r_e, e_b2,
      g_g, g_b, w1r_g, g_b1, w2r_g, g_b2,
      out_n, out_e, out_g, N, Me, nbE);
}